// Round 8
// baseline (365.962 us; speedup 1.0000x reference)
//
#include <hip/hip_runtime.h>
#include <hip/hip_fp16.h>
#include <math.h>

#define N_NODES 50000
#define N_EDGES 1000000
#define E_PAD   (N_EDGES + 8)               // padded plane stride for masked unroll
#define F_IN    165
#define HID     128
#define HEADS   4
#define F_OUT   32
#define NEG_SLOPE 0.2f
#define NB_SCAN  ((N_NODES + 255) / 256)   // 196 scan blocks
#define NPART    8                          // dst partitions (= XCDs)
#define PART_SZ  (N_NODES / NPART)          // 6250, exact
#define SCHUNKS  256                        // edge chunks for scatter

// ==== fused GEMM + attention logits ==========================================
// out[N,128] = X[N,K] @ W[K,128] stored as fp16; el/er[N,4] fp32 in epilogue.
// 64x64 tile (2 heads) per block; 256 threads; 4x4 per thread; K tiled by 32.
// T14 async-STAGE: next tile -> registers before compute, ds_write after
// barrier, so the vmcnt wait is covered by 32x16 FMAs.
template <int K>
__global__ __launch_bounds__(256) void gemm_fused(const float* __restrict__ X,
                                                  const float* __restrict__ W,
                                                  const float* __restrict__ al,
                                                  const float* __restrict__ ar,
                                                  __half* __restrict__ feat,
                                                  float* __restrict__ el,
                                                  float* __restrict__ er) {
    constexpr int KT = 32;
    constexpr int NKT = (K + KT - 1) / KT;
    constexpr int LDR = 68;
    __shared__ float xs[KT * LDR];          // xs[j*LDR + r] = X[base+r][k0+j]

    const int rb   = blockIdx.x >> 1;
    const int cb   = blockIdx.x & 1;
    const int base = rb * 64;
    const int co   = cb * 64;
    const int tid  = threadIdx.x;
    const int nrows = min(64, N_NODES - base);

    const int cg = tid & 15;                // col group: 4 cols at c0
    const int rg = tid >> 4;                // row group: 4 rows at r0
    const int c0 = cg * 4;
    const int r0 = rg * 4;
    const int hloc = cg >> 3;
    const int h = cb * 2 + hloc;

    const int sr = tid >> 5;                // staging row base (0..7)
    const int sj = tid & 31;                // staging k offset (0..31)

    float stg[8];
#pragma unroll
    for (int s = 0; s < 8; ++s) {
        const int r = sr + 8 * s;
        stg[s] = (r < nrows && sj < K) ? X[(size_t)(base + r) * K + sj] : 0.f;
    }
#pragma unroll
    for (int s = 0; s < 8; ++s) xs[sj * LDR + sr + 8 * s] = stg[s];
    __syncthreads();

    float acc[4][4];
#pragma unroll
    for (int i = 0; i < 4; ++i)
#pragma unroll
        for (int j = 0; j < 4; ++j) acc[i][j] = 0.f;

    for (int t = 0; t < NKT; ++t) {
        const int k0 = t * KT;
        if (t + 1 < NKT) {
            const int nk0 = k0 + KT;
#pragma unroll
            for (int s = 0; s < 8; ++s) {
                const int r = sr + 8 * s;
                stg[s] = (r < nrows && nk0 + sj < K)
                             ? X[(size_t)(base + r) * K + nk0 + sj] : 0.f;
            }
        }
        const int cnt = min(KT, K - k0);
        if (cnt == KT) {
#pragma unroll
            for (int j = 0; j < KT; ++j) {
                const float4 wv = *(const float4*)&W[(size_t)(k0 + j) * HID + co + c0];
                const float4 xr = *(const float4*)&xs[j * LDR + r0];
                acc[0][0] += xr.x * wv.x; acc[0][1] += xr.x * wv.y;
                acc[0][2] += xr.x * wv.z; acc[0][3] += xr.x * wv.w;
                acc[1][0] += xr.y * wv.x; acc[1][1] += xr.y * wv.y;
                acc[1][2] += xr.y * wv.z; acc[1][3] += xr.y * wv.w;
                acc[2][0] += xr.z * wv.x; acc[2][1] += xr.z * wv.y;
                acc[2][2] += xr.z * wv.z; acc[2][3] += xr.z * wv.w;
                acc[3][0] += xr.w * wv.x; acc[3][1] += xr.w * wv.y;
                acc[3][2] += xr.w * wv.z; acc[3][3] += xr.w * wv.w;
            }
        } else {
            for (int j = 0; j < cnt; ++j) {
                const float4 wv = *(const float4*)&W[(size_t)(k0 + j) * HID + co + c0];
                const float4 xr = *(const float4*)&xs[j * LDR + r0];
                acc[0][0] += xr.x * wv.x; acc[0][1] += xr.x * wv.y;
                acc[0][2] += xr.x * wv.z; acc[0][3] += xr.x * wv.w;
                acc[1][0] += xr.y * wv.x; acc[1][1] += xr.y * wv.y;
                acc[1][2] += xr.y * wv.z; acc[1][3] += xr.y * wv.w;
                acc[2][0] += xr.z * wv.x; acc[2][1] += xr.z * wv.y;
                acc[2][2] += xr.z * wv.z; acc[2][3] += xr.z * wv.w;
                acc[3][0] += xr.w * wv.x; acc[3][1] += xr.w * wv.y;
                acc[3][2] += xr.w * wv.z; acc[3][3] += xr.w * wv.w;
            }
        }
        if (t + 1 < NKT) {
            __syncthreads();
#pragma unroll
            for (int s = 0; s < 8; ++s) xs[sj * LDR + sr + 8 * s] = stg[s];
            __syncthreads();
        }
    }

    const int f0 = (cg & 7) * 4;
    float alv[4], arv[4];
#pragma unroll
    for (int j = 0; j < 4; ++j) {
        alv[j] = al[h * F_OUT + f0 + j];
        arv[j] = ar[h * F_OUT + f0 + j];
    }

#pragma unroll
    for (int i = 0; i < 4; ++i) {
        const int node = base + r0 + i;
        float pl = acc[i][0] * alv[0] + acc[i][1] * alv[1] +
                   acc[i][2] * alv[2] + acc[i][3] * alv[3];
        float pr = acc[i][0] * arv[0] + acc[i][1] * arv[1] +
                   acc[i][2] * arv[2] + acc[i][3] * arv[3];
        pl += __shfl_xor(pl, 1); pr += __shfl_xor(pr, 1);
        pl += __shfl_xor(pl, 2); pr += __shfl_xor(pr, 2);
        pl += __shfl_xor(pl, 4); pr += __shfl_xor(pr, 4);
        if (r0 + i < nrows) {
            const __half2 p0 = __floats2half2_rn(acc[i][0], acc[i][1]);
            const __half2 p1 = __floats2half2_rn(acc[i][2], acc[i][3]);
            uint2 u;
            u.x = *(const unsigned int*)&p0;
            u.y = *(const unsigned int*)&p1;
            *(uint2*)&feat[(size_t)node * HID + co + c0] = u;
            if ((cg & 7) == 0) {
                el[node * HEADS + h] = pl;
                er[node * HEADS + h] = pr;
            }
        }
    }
}

// ================= CSR build (once per launch, reused by both layers) ========

__global__ __launch_bounds__(256) void zero_counts(int* __restrict__ counts) {
    const int i = blockIdx.x * 256 + threadIdx.x;
    if (i < N_NODES) counts[i] = 0;
}

__global__ __launch_bounds__(256) void hist_dst(const int* __restrict__ dst,
                                                int* __restrict__ counts) {
    const int e = blockIdx.x * 256 + threadIdx.x;
    if (e < N_EDGES) atomicAdd(&counts[dst[e]], 1);
}

__global__ __launch_bounds__(256) void scan_local(const int* __restrict__ counts,
                                                  int* __restrict__ rowptr,
                                                  int* __restrict__ blockSums) {
    __shared__ int tmp[256];
    const int i = blockIdx.x * 256 + threadIdx.x;
    const int v = (i < N_NODES) ? counts[i] : 0;
    tmp[threadIdx.x] = v;
    __syncthreads();
#pragma unroll
    for (int off = 1; off < 256; off <<= 1) {
        int t = (threadIdx.x >= off) ? tmp[threadIdx.x - off] : 0;
        __syncthreads();
        tmp[threadIdx.x] += t;
        __syncthreads();
    }
    if (i < N_NODES) rowptr[i] = tmp[threadIdx.x] - v;
    if (threadIdx.x == 255) blockSums[blockIdx.x] = tmp[255];
}

__global__ __launch_bounds__(256) void scan_sums(int* __restrict__ blockSums) {
    __shared__ int tmp[256];
    const int v = (threadIdx.x < NB_SCAN) ? blockSums[threadIdx.x] : 0;
    tmp[threadIdx.x] = v;
    __syncthreads();
#pragma unroll
    for (int off = 1; off < 256; off <<= 1) {
        int t = (threadIdx.x >= off) ? tmp[threadIdx.x - off] : 0;
        __syncthreads();
        tmp[threadIdx.x] += t;
        __syncthreads();
    }
    if (threadIdx.x < NB_SCAN) blockSums[threadIdx.x] = tmp[threadIdx.x] - v;
}

__global__ __launch_bounds__(256) void add_offsets(int* __restrict__ rowptr,
                                                   const int* __restrict__ blockSums,
                                                   int* __restrict__ cursor) {
    const int i = blockIdx.x * 256 + threadIdx.x;
    if (i < N_NODES) {
        const int r = rowptr[i] + blockSums[blockIdx.x];
        rowptr[i] = r;
        cursor[i] = r;
    }
    if (i == 0) rowptr[N_NODES] = N_EDGES;
}

// XCD-partitioned scatter (R6): partition p = blockIdx&7 owns one dst range so
// all writers of a csr_src line sit on one XCD L2.
__global__ __launch_bounds__(256) void scatter_csr_part(const int* __restrict__ src,
                                                        const int* __restrict__ dst,
                                                        int* __restrict__ cursor,
                                                        int* __restrict__ csr_src) {
    const int part  = blockIdx.x & (NPART - 1);
    const int chunk = blockIdx.x >> 3;
    constexpr int CE = (N_EDGES + SCHUNKS - 1) / SCHUNKS;   // 3907
    const int e0 = chunk * CE;
    const int e1 = min(e0 + CE, N_EDGES);
    for (int e = e0 + threadIdx.x; e < e1; e += 256) {
        const int d = dst[e];
        if (d / PART_SZ == part) {
            const int pos = atomicAdd(&cursor[d], 1);
            csr_src[pos] = src[e];
        }
    }
}

// ===== per-edge softmax weights (unnormalized), fp16 planes w[h][e] ==========
// wave per dst node; lanes = edges. Each lane computes all 4 heads for one
// edge (exp redundancy 16x lower than feature-parallel layout). Writes are
// coalesced 2B stores per plane. el gather is a random float4 in an 800KB
// table -> L2-resident.
__global__ __launch_bounds__(256) void edge_weights(const int* __restrict__ rowptr,
                                                    const int* __restrict__ csr_src,
                                                    const float* __restrict__ el,
                                                    const float* __restrict__ er,
                                                    __half* __restrict__ w) {
    const int d = (blockIdx.x * 256 + threadIdx.x) >> 6;
    if (d >= N_NODES) return;
    const int lane = threadIdx.x & 63;
    const int start = rowptr[d], end = rowptr[d + 1];
    if (start >= end) return;
    const float4 er4 = *(const float4*)&er[(unsigned)d * 4u];
    for (int e = start + lane; e < end; e += 64) {
        const unsigned s = (unsigned)csr_src[e];
        const float4 el4 = *(const float4*)&el[s * 4u];
        float v0 = el4.x + er4.x; v0 = fmaxf(v0, NEG_SLOPE * v0);
        float v1 = el4.y + er4.y; v1 = fmaxf(v1, NEG_SLOPE * v1);
        float v2 = el4.z + er4.z; v2 = fmaxf(v2, NEG_SLOPE * v2);
        float v3 = el4.w + er4.w; v3 = fmaxf(v3, NEG_SLOPE * v3);
        w[(unsigned)e]                = __float2half_rn(__expf(v0));
        w[E_PAD + (unsigned)e]        = __float2half_rn(__expf(v1));
        w[2u * E_PAD + (unsigned)e]   = __float2half_rn(__expf(v2));
        w[3u * E_PAD + (unsigned)e]   = __float2half_rn(__expf(v3));
    }
}

// ===== lean GAT aggregation: w-weighted gather + normalize + ReLU ============
// Per edge: 1 ushort broadcast load (w), 1 shfl (src), 1 fp16 row gather,
// 2 FMA + 1 add. Mask-unrolled x8, no serial tail (w planes padded +8;
// out-of-range slots contribute x=0; junk gathers hit a clamped valid row).
// FUSE_HEADS: layer-2 variant computes both MLP heads from in-register h2.
template <bool FUSE_HEADS>
__global__ __launch_bounds__(256) void gat_aggregate(const int* __restrict__ rowptr,
                                                     const int* __restrict__ csr_src,
                                                     const __half* __restrict__ w,
                                                     const __half* __restrict__ feat,
                                                     float* __restrict__ outh,
                                                     const float* __restrict__ Wc1,
                                                     const float* __restrict__ bc1,
                                                     const float* __restrict__ Wc2,
                                                     const float* __restrict__ bc2,
                                                     const float* __restrict__ Wf1,
                                                     const float* __restrict__ bf1,
                                                     const float* __restrict__ Wf2,
                                                     const float* __restrict__ bf2,
                                                     float* __restrict__ out) {
    const int d = (blockIdx.x * 256 + threadIdx.x) >> 6;
    if (d >= N_NODES) return;
    const int lane = threadIdx.x & 63;
    const int h = lane >> 4;
    const int start = rowptr[d], end = rowptr[d + 1];
    const __half2* __restrict__ feat2 = (const __half2*)feat;   // row stride 64
    const __half* __restrict__ wp = w + (unsigned)h * (unsigned)E_PAD;

    float denom = 0.f, ax = 0.f, ay = 0.f;
    for (int chunk = start; chunk < end; chunk += 64) {
        const int cnt = min(64, end - chunk);
        const int idx = chunk + lane;
        const int sv = csr_src[idx < end ? idx : start];
        for (int i = 0; i < cnt; i += 8) {
            float x[8];
            unsigned s[8];
            __half2 q[8];
#pragma unroll
            for (int j = 0; j < 8; ++j)
                x[j] = __half2float(wp[(unsigned)(chunk + i + j)]);
#pragma unroll
            for (int j = 0; j < 8; ++j)
                s[j] = (unsigned)__shfl(sv, i + j);
#pragma unroll
            for (int j = 0; j < 8; ++j)
                q[j] = feat2[s[j] * 64u + (unsigned)lane];
#pragma unroll
            for (int j = 0; j < 8; ++j)
                if (i + j >= cnt) x[j] = 0.f;     // wave-uniform mask
#pragma unroll
            for (int j = 0; j < 8; ++j) {
                const float2 f = __half22float2(q[j]);
                denom += x[j];
                ax += f.x * x[j];
                ay += f.y * x[j];
            }
        }
    }
    const float inv = 1.f / fmaxf(denom, 1e-9f);
    const float hx = fmaxf(ax * inv, 0.f);
    const float hy = fmaxf(ay * inv, 0.f);

    if (!FUSE_HEADS) {
        *(float2*)&outh[(size_t)d * HID + lane * 2] = make_float2(hx, hy);
        return;
    }

    float ac[10], af[10];
#pragma unroll
    for (int o = 0; o < 10; ++o) {
        ac[o] = hx * Wc1[(lane * 2) * 10 + o] + hy * Wc1[(lane * 2 + 1) * 10 + o];
        af[o] = hx * Wf1[(lane * 2) * 10 + o] + hy * Wf1[(lane * 2 + 1) * 10 + o];
    }
#pragma unroll
    for (int off = 32; off >= 1; off >>= 1) {
#pragma unroll
        for (int o = 0; o < 10; ++o) {
            ac[o] += __shfl_xor(ac[o], off);
            af[o] += __shfl_xor(af[o], off);
        }
    }
    if (lane == 0) {
        float pc = bc2[0], pf = bf2[0];
#pragma unroll
        for (int o = 0; o < 10; ++o) {
            pc += fmaxf(ac[o] + bc1[o], 0.f) * Wc2[o];
            pf += fmaxf(af[o] + bf1[o], 0.f) * Wf2[o];
        }
        out[d] = pc;
        out[N_NODES + d] = 1.0f / (1.0f + __expf(-pf));
    }
}

extern "C" void kernel_launch(void* const* d_in, const int* in_sizes, int n_in,
                              void* d_out, int out_size, void* d_ws, size_t ws_size,
                              hipStream_t stream) {
    const float* features = (const float*)d_in[0];
    const int*   src      = (const int*)d_in[1];
    const int*   dst      = (const int*)d_in[2];
    const float* W1  = (const float*)d_in[3];
    const float* al1 = (const float*)d_in[4];
    const float* ar1 = (const float*)d_in[5];
    const float* W2  = (const float*)d_in[6];
    const float* al2 = (const float*)d_in[7];
    const float* ar2 = (const float*)d_in[8];
    const float* Wc1 = (const float*)d_in[9];
    const float* bc1 = (const float*)d_in[10];
    const float* Wc2 = (const float*)d_in[11];
    const float* bc2 = (const float*)d_in[12];
    const float* Wf1 = (const float*)d_in[13];
    const float* bf1 = (const float*)d_in[14];
    const float* Wf2 = (const float*)d_in[15];
    const float* bf2 = (const float*)d_in[16];
    float* out = (float*)d_out;

    // workspace layout (float-sized slots):
    // featslot[128N]: first half = feat fp16 (12.8MB), second half = w planes
    //                 (4 x E_PAD fp16 = 8MB) -- both live simultaneously.
    // hbuf[128N] | el[4N] | er[4N] | counts[N] | rowptr[N+1] | cursor[N]
    // | blockSums[256] | csr_src[E]
    float* featslot = (float*)d_ws;
    float* hbuf = featslot + (size_t)N_NODES * HID;
    float* el   = hbuf + (size_t)N_NODES * HID;
    float* er   = el + (size_t)N_NODES * HEADS;
    int* counts    = (int*)(er + (size_t)N_NODES * HEADS);
    int* rowptr    = counts + N_NODES;
    int* cursor    = rowptr + N_NODES + 1;
    int* blockSums = cursor + N_NODES;
    int* csr_src   = blockSums + 256;
    __half* feat   = (__half*)featslot;
    __half* wbuf   = (__half*)(featslot + (size_t)N_NODES * 64);

    const int nodeWaveBlocks = (N_NODES * 64 + 255) / 256;   // 12500
    const int edgeBlocks     = (N_EDGES + 255) / 256;        // 3907
    const int gemmBlocks     = ((N_NODES + 63) / 64) * 2;    // 1564
    const int scatterBlocks  = SCHUNKS * NPART;              // 2048

    // ---------- CSR build (dst-sorted incidence), reused by both layers ------
    zero_counts<<<NB_SCAN, 256, 0, stream>>>(counts);
    hist_dst<<<edgeBlocks, 256, 0, stream>>>(dst, counts);
    scan_local<<<NB_SCAN, 256, 0, stream>>>(counts, rowptr, blockSums);
    scan_sums<<<1, 256, 0, stream>>>(blockSums);
    add_offsets<<<NB_SCAN, 256, 0, stream>>>(rowptr, blockSums, cursor);
    scatter_csr_part<<<scatterBlocks, 256, 0, stream>>>(src, dst, cursor, csr_src);

    // ---------- layer 1 ----------
    gemm_fused<F_IN><<<gemmBlocks, 256, 0, stream>>>(features, W1, al1, ar1,
                                                     feat, el, er);
    edge_weights<<<nodeWaveBlocks, 256, 0, stream>>>(rowptr, csr_src, el, er, wbuf);
    gat_aggregate<false><<<nodeWaveBlocks, 256, 0, stream>>>(
        rowptr, csr_src, wbuf, feat, hbuf,
        Wc1, bc1, Wc2, bc2, Wf1, bf1, Wf2, bf2, out);

    // ---------- layer 2 (heads fused into aggregation epilogue) ----------
    gemm_fused<HID><<<gemmBlocks, 256, 0, stream>>>(hbuf, W2, al2, ar2,
                                                    feat, el, er);
    edge_weights<<<nodeWaveBlocks, 256, 0, stream>>>(rowptr, csr_src, el, er, wbuf);
    gat_aggregate<true><<<nodeWaveBlocks, 256, 0, stream>>>(
        rowptr, csr_src, wbuf, feat, nullptr,
        Wc1, bc1, Wc2, bc2, Wf1, bf1, Wf2, bf2, out);
}

// Round 9
// 287.752 us; speedup vs baseline: 1.2718x; 1.2718x over previous
//
#include <hip/hip_runtime.h>
#include <hip/hip_fp16.h>
#include <math.h>

#define N_NODES 50000
#define N_EDGES 1000000
#define F_IN    165
#define KP1     176                         // F_IN padded to 16
#define HID     128
#define HEADS   4
#define F_OUT   32
#define NEG_SLOPE 0.2f
#define NB_SCAN  ((N_NODES + 255) / 256)   // 196 scan blocks
#define NPART    8                          // dst partitions (= XCDs)
#define PART_SZ  (N_NODES / NPART)          // 6250, exact
#define SCHUNKS  256                        // edge chunks for scatter

typedef _Float16 half4v __attribute__((ext_vector_type(4)));
typedef float    f32x4  __attribute__((ext_vector_type(4)));

// ===== prep: features fp32 -> fp16 padded [N][KP1] ==========================
__global__ __launch_bounds__(256) void cvt_features(const float* __restrict__ X,
                                                    __half* __restrict__ Xh) {
    const long long i = (long long)blockIdx.x * 256 + threadIdx.x;
    if (i >= (long long)N_NODES * KP1) return;
    const int n = (int)(i / KP1);
    const int k = (int)(i - (long long)n * KP1);
    Xh[i] = (k < F_IN) ? __float2half_rn(X[(long long)n * F_IN + k])
                       : __float2half_rn(0.f);
}

// ===== prep: pack W[K][128] fp32 into MFMA B-fragment order fp16 =============
// Wp[((kt*8 + ct)*64 + lane)*4 + i] = W[kt*16 + 4*(lane>>4) + i][ct*16 + (lane&15)]
__global__ __launch_bounds__(256) void pack_w(const float* __restrict__ W,
                                              __half* __restrict__ Wp,
                                              int K, int ksteps) {
    const int idx = blockIdx.x * 256 + threadIdx.x;   // (kt*8+ct)*64 + lane
    if (idx >= ksteps * 8 * 64) return;
    const int lane = idx & 63;
    const int tile = idx >> 6;
    const int ct = tile & 7;
    const int kt = tile >> 3;
    const int col = ct * 16 + (lane & 15);
    const int k0 = kt * 16 + 4 * (lane >> 4);
#pragma unroll
    for (int i = 0; i < 4; ++i) {
        const int k = k0 + i;
        Wp[(size_t)idx * 4 + i] = (k < K) ? __float2half_rn(W[(size_t)k * HID + col])
                                          : __float2half_rn(0.f);
    }
}

// ===== MFMA GEMM + fused attention logits =====================================
// feat[N,128](fp16) = Xh[N,KP](fp16) @ W(packed); el/er[N,4] fp32 in epilogue.
// Block = 4 waves; wave w owns rows base+16w..+15 x ALL 128 cols (8 MFMA tiles).
// No LDS, no barriers. B loads coalesced 8B/lane from packed Wp (L2-resident).
template <int KSTEPS, int KP>
__global__ __launch_bounds__(256) void gemm_mfma(const __half* __restrict__ Xh,
                                                 const __half* __restrict__ Wp,
                                                 const float* __restrict__ al,
                                                 const float* __restrict__ ar,
                                                 __half* __restrict__ feat,
                                                 float* __restrict__ el,
                                                 float* __restrict__ er) {
    const int tid  = threadIdx.x;
    const int wav  = tid >> 6;
    const int lane = tid & 63;
    const int base = blockIdx.x * 64 + wav * 16;     // 16-row slice per wave
    if (base >= N_NODES) return;
    const int lr = lane & 15;                         // row (A) / col (B,D)
    const int lq = lane >> 4;                         // k-quad / row-quad

    f32x4 acc[8];
#pragma unroll
    for (int ct = 0; ct < 8; ++ct) acc[ct] = (f32x4){0.f, 0.f, 0.f, 0.f};

    const __half* arow = Xh + (size_t)(base + lr) * KP + 4 * lq;
    for (int kt = 0; kt < KSTEPS; ++kt) {
        const half4v a = *reinterpret_cast<const half4v*>(arow + kt * 16);
        const __half* bp = Wp + ((size_t)kt * 8 * 64 + lane) * 4;
#pragma unroll
        for (int ct = 0; ct < 8; ++ct) {
            const half4v b = *reinterpret_cast<const half4v*>(bp + (size_t)ct * 256);
            acc[ct] = __builtin_amdgcn_mfma_f32_16x16x16f16(a, b, acc[ct], 0, 0, 0);
        }
    }

    // attention vectors: alv[ct] = al[head(ct)][(ct&1)*16 + lr]
    float alv[8], arv[8];
#pragma unroll
    for (int ct = 0; ct < 8; ++ct) {
        const int h = ct >> 1;
        const int f = (ct & 1) * 16 + lr;
        alv[ct] = al[h * F_OUT + f];
        arv[ct] = ar[h * F_OUT + f];
    }

#pragma unroll
    for (int i = 0; i < 4; ++i) {
        const int node = base + 4 * lq + i;           // D row = 4*lq + i
        // feat write: col = ct*16 + lr
#pragma unroll
        for (int ct = 0; ct < 8; ++ct)
            feat[(size_t)node * HID + ct * 16 + lr] = __float2half_rn(acc[ct][i]);
        // el/er per head: reduce over the 16 lanes of this row group
#pragma unroll
        for (int h = 0; h < 4; ++h) {
            float pl = acc[2 * h][i] * alv[2 * h] + acc[2 * h + 1][i] * alv[2 * h + 1];
            float pr = acc[2 * h][i] * arv[2 * h] + acc[2 * h + 1][i] * arv[2 * h + 1];
            pl += __shfl_xor(pl, 1); pr += __shfl_xor(pr, 1);
            pl += __shfl_xor(pl, 2); pr += __shfl_xor(pr, 2);
            pl += __shfl_xor(pl, 4); pr += __shfl_xor(pr, 4);
            pl += __shfl_xor(pl, 8); pr += __shfl_xor(pr, 8);
            if (lr == 0) {
                el[node * HEADS + h] = pl;
                er[node * HEADS + h] = pr;
            }
        }
    }
}

// ================= CSR build (once per launch, reused by both layers) ========

__global__ __launch_bounds__(256) void zero_counts(int* __restrict__ counts) {
    const int i = blockIdx.x * 256 + threadIdx.x;
    if (i < N_NODES) counts[i] = 0;
}

__global__ __launch_bounds__(256) void hist_dst(const int* __restrict__ dst,
                                                int* __restrict__ counts) {
    const int e = blockIdx.x * 256 + threadIdx.x;
    if (e < N_EDGES) atomicAdd(&counts[dst[e]], 1);
}

__global__ __launch_bounds__(256) void scan_local(const int* __restrict__ counts,
                                                  int* __restrict__ rowptr,
                                                  int* __restrict__ blockSums) {
    __shared__ int tmp[256];
    const int i = blockIdx.x * 256 + threadIdx.x;
    const int v = (i < N_NODES) ? counts[i] : 0;
    tmp[threadIdx.x] = v;
    __syncthreads();
#pragma unroll
    for (int off = 1; off < 256; off <<= 1) {
        int t = (threadIdx.x >= off) ? tmp[threadIdx.x - off] : 0;
        __syncthreads();
        tmp[threadIdx.x] += t;
        __syncthreads();
    }
    if (i < N_NODES) rowptr[i] = tmp[threadIdx.x] - v;
    if (threadIdx.x == 255) blockSums[blockIdx.x] = tmp[255];
}

__global__ __launch_bounds__(256) void scan_sums(int* __restrict__ blockSums) {
    __shared__ int tmp[256];
    const int v = (threadIdx.x < NB_SCAN) ? blockSums[threadIdx.x] : 0;
    tmp[threadIdx.x] = v;
    __syncthreads();
#pragma unroll
    for (int off = 1; off < 256; off <<= 1) {
        int t = (threadIdx.x >= off) ? tmp[threadIdx.x - off] : 0;
        __syncthreads();
        tmp[threadIdx.x] += t;
        __syncthreads();
    }
    if (threadIdx.x < NB_SCAN) blockSums[threadIdx.x] = tmp[threadIdx.x] - v;
}

__global__ __launch_bounds__(256) void add_offsets(int* __restrict__ rowptr,
                                                   const int* __restrict__ blockSums,
                                                   int* __restrict__ cursor) {
    const int i = blockIdx.x * 256 + threadIdx.x;
    if (i < N_NODES) {
        const int r = rowptr[i] + blockSums[blockIdx.x];
        rowptr[i] = r;
        cursor[i] = r;
    }
    if (i == 0) rowptr[N_NODES] = N_EDGES;
}

// XCD-partitioned scatter: partition p = blockIdx&7 owns one dst range so all
// writers of a csr_src line sit on one XCD L2.
__global__ __launch_bounds__(256) void scatter_csr_part(const int* __restrict__ src,
                                                        const int* __restrict__ dst,
                                                        int* __restrict__ cursor,
                                                        int* __restrict__ csr_src) {
    const int part  = blockIdx.x & (NPART - 1);
    const int chunk = blockIdx.x >> 3;
    constexpr int CE = (N_EDGES + SCHUNKS - 1) / SCHUNKS;   // 3907
    const int e0 = chunk * CE;
    const int e1 = min(e0 + CE, N_EDGES);
    for (int e = e0 + threadIdx.x; e < e1; e += 256) {
        const int d = dst[e];
        if (d / PART_SZ == part) {
            const int pos = atomicAdd(&cursor[d], 1);
            csr_src[pos] = src[e];
        }
    }
}

// ===== fused GAT aggregation (R7 form): exp-gather + normalize + ReLU ========
// feat fp16; math fp32; edge loop unrolled x4; no atomics, no max pass.
// Non-fused variant writes h as fp16 (direct input to layer-2 MFMA GEMM).
// FUSE_HEADS: layer-2 variant computes both MLP heads from in-register h2.
template <bool FUSE_HEADS>
__global__ __launch_bounds__(256) void gat_aggregate(const int* __restrict__ rowptr,
                                                     const int* __restrict__ csr_src,
                                                     const float* __restrict__ el,
                                                     const float* __restrict__ er,
                                                     const __half* __restrict__ feat,
                                                     __half* __restrict__ outh,
                                                     const float* __restrict__ Wc1,
                                                     const float* __restrict__ bc1,
                                                     const float* __restrict__ Wc2,
                                                     const float* __restrict__ bc2,
                                                     const float* __restrict__ Wf1,
                                                     const float* __restrict__ bf1,
                                                     const float* __restrict__ Wf2,
                                                     const float* __restrict__ bf2,
                                                     float* __restrict__ out) {
    const int d = (blockIdx.x * 256 + threadIdx.x) >> 6;
    if (d >= N_NODES) return;
    const int lane = threadIdx.x & 63;
    const int h = lane >> 4;
    const int start = rowptr[d], end = rowptr[d + 1];
    const float erd = er[d * HEADS + h];
    const __half2* __restrict__ feat2 = (const __half2*)feat;   // row stride 64

    float denom = 0.f, ax = 0.f, ay = 0.f;
    for (int chunk = start; chunk < end; chunk += 64) {
        const int cnt = min(64, end - chunk);
        const int idx = chunk + lane;
        const int sv = csr_src[idx < end ? idx : start];
        int i = 0;
        for (; i + 4 <= cnt; i += 4) {
            const int s0 = __shfl(sv, i);
            const int s1 = __shfl(sv, i + 1);
            const int s2 = __shfl(sv, i + 2);
            const int s3 = __shfl(sv, i + 3);
            const float e0 = el[s0 * HEADS + h];
            const float e1 = el[s1 * HEADS + h];
            const float e2 = el[s2 * HEADS + h];
            const float e3 = el[s3 * HEADS + h];
            const __half2 q0 = feat2[(size_t)s0 * 64 + lane];
            const __half2 q1 = feat2[(size_t)s1 * 64 + lane];
            const __half2 q2 = feat2[(size_t)s2 * 64 + lane];
            const __half2 q3 = feat2[(size_t)s3 * 64 + lane];
            float v0 = e0 + erd; v0 = v0 > 0.f ? v0 : NEG_SLOPE * v0;
            float v1 = e1 + erd; v1 = v1 > 0.f ? v1 : NEG_SLOPE * v1;
            float v2 = e2 + erd; v2 = v2 > 0.f ? v2 : NEG_SLOPE * v2;
            float v3 = e3 + erd; v3 = v3 > 0.f ? v3 : NEG_SLOPE * v3;
            const float x0 = __expf(v0);
            const float x1 = __expf(v1);
            const float x2 = __expf(v2);
            const float x3 = __expf(v3);
            const float2 f0 = __half22float2(q0);
            const float2 f1 = __half22float2(q1);
            const float2 f2 = __half22float2(q2);
            const float2 f3 = __half22float2(q3);
            denom += (x0 + x1) + (x2 + x3);
            ax += f0.x * x0 + f1.x * x1 + f2.x * x2 + f3.x * x3;
            ay += f0.y * x0 + f1.y * x1 + f2.y * x2 + f3.y * x3;
        }
        for (; i < cnt; ++i) {
            const int s0 = __shfl(sv, i);
            const float e0 = el[s0 * HEADS + h];
            const __half2 q0 = feat2[(size_t)s0 * 64 + lane];
            float v0 = e0 + erd; v0 = v0 > 0.f ? v0 : NEG_SLOPE * v0;
            const float x0 = __expf(v0);
            const float2 f0 = __half22float2(q0);
            denom += x0;
            ax += f0.x * x0;
            ay += f0.y * x0;
        }
    }
    const float inv = 1.f / fmaxf(denom, 1e-9f);
    const float hx = fmaxf(ax * inv, 0.f);
    const float hy = fmaxf(ay * inv, 0.f);

    if (!FUSE_HEADS) {
        ((__half2*)outh)[(size_t)d * 64 + lane] = __floats2half2_rn(hx, hy);
        return;
    }

    float ac[10], af[10];
#pragma unroll
    for (int o = 0; o < 10; ++o) {
        ac[o] = hx * Wc1[(lane * 2) * 10 + o] + hy * Wc1[(lane * 2 + 1) * 10 + o];
        af[o] = hx * Wf1[(lane * 2) * 10 + o] + hy * Wf1[(lane * 2 + 1) * 10 + o];
    }
#pragma unroll
    for (int off = 32; off >= 1; off >>= 1) {
#pragma unroll
        for (int o = 0; o < 10; ++o) {
            ac[o] += __shfl_xor(ac[o], off);
            af[o] += __shfl_xor(af[o], off);
        }
    }
    if (lane == 0) {
        float pc = bc2[0], pf = bf2[0];
#pragma unroll
        for (int o = 0; o < 10; ++o) {
            pc += fmaxf(ac[o] + bc1[o], 0.f) * Wc2[o];
            pf += fmaxf(af[o] + bf1[o], 0.f) * Wf2[o];
        }
        out[d] = pc;
        out[N_NODES + d] = 1.0f / (1.0f + __expf(-pf));
    }
}

extern "C" void kernel_launch(void* const* d_in, const int* in_sizes, int n_in,
                              void* d_out, int out_size, void* d_ws, size_t ws_size,
                              hipStream_t stream) {
    const float* features = (const float*)d_in[0];
    const int*   src      = (const int*)d_in[1];
    const int*   dst      = (const int*)d_in[2];
    const float* W1  = (const float*)d_in[3];
    const float* al1 = (const float*)d_in[4];
    const float* ar1 = (const float*)d_in[5];
    const float* W2  = (const float*)d_in[6];
    const float* al2 = (const float*)d_in[7];
    const float* ar2 = (const float*)d_in[8];
    const float* Wc1 = (const float*)d_in[9];
    const float* bc1 = (const float*)d_in[10];
    const float* Wc2 = (const float*)d_in[11];
    const float* bc2 = (const float*)d_in[12];
    const float* Wf1 = (const float*)d_in[13];
    const float* bf1 = (const float*)d_in[14];
    const float* Wf2 = (const float*)d_in[15];
    const float* bf2 = (const float*)d_in[16];
    float* out = (float*)d_out;

    // workspace layout (halfs first, then fp32, then ints):
    // Xh[N*176] | feat[N*128] | hbuf[N*128] | Wp1[11*8*256] | Wp2[8*8*256]
    // | el[4N] f32 | er[4N] f32 | counts[N] | rowptr[N+1] | cursor[N]
    // | blockSums[256] | csr_src[E]
    __half* Xh   = (__half*)d_ws;
    __half* feat = Xh + (size_t)N_NODES * KP1;
    __half* hbuf = feat + (size_t)N_NODES * HID;
    __half* Wp1  = hbuf + (size_t)N_NODES * HID;
    __half* Wp2  = Wp1 + 11 * 8 * 64 * 4;
    float*  el   = (float*)(Wp2 + 8 * 8 * 64 * 4);
    float*  er   = el + (size_t)N_NODES * HEADS;
    int* counts    = (int*)(er + (size_t)N_NODES * HEADS);
    int* rowptr    = counts + N_NODES;
    int* cursor    = rowptr + N_NODES + 1;
    int* blockSums = cursor + N_NODES;
    int* csr_src   = blockSums + 256;

    const int nodeWaveBlocks = (N_NODES * 64 + 255) / 256;   // 12500
    const int edgeBlocks     = (N_EDGES + 255) / 256;        // 3907
    const int gemmBlocks     = (N_NODES + 63) / 64;          // 782
    const int scatterBlocks  = SCHUNKS * NPART;              // 2048
    const int cvtBlocks      = (int)(((long long)N_NODES * KP1 + 255) / 256);

    // ---------- prep: fp16 conversions + W fragment packing -----------------
    cvt_features<<<cvtBlocks, 256, 0, stream>>>(features, Xh);
    pack_w<<<(11 * 8 * 64 + 255) / 256, 256, 0, stream>>>(W1, Wp1, F_IN, 11);
    pack_w<<<(8 * 8 * 64 + 255) / 256, 256, 0, stream>>>(W2, Wp2, HID, 8);

    // ---------- CSR build (dst-sorted incidence), reused by both layers ------
    zero_counts<<<NB_SCAN, 256, 0, stream>>>(counts);
    hist_dst<<<edgeBlocks, 256, 0, stream>>>(dst, counts);
    scan_local<<<NB_SCAN, 256, 0, stream>>>(counts, rowptr, blockSums);
    scan_sums<<<1, 256, 0, stream>>>(blockSums);
    add_offsets<<<NB_SCAN, 256, 0, stream>>>(rowptr, blockSums, cursor);
    scatter_csr_part<<<scatterBlocks, 256, 0, stream>>>(src, dst, cursor, csr_src);

    // ---------- layer 1 ----------
    gemm_mfma<11, KP1><<<gemmBlocks, 256, 0, stream>>>(Xh, Wp1, al1, ar1,
                                                       feat, el, er);
    gat_aggregate<false><<<nodeWaveBlocks, 256, 0, stream>>>(
        rowptr, csr_src, el, er, feat, hbuf,
        Wc1, bc1, Wc2, bc2, Wf1, bf1, Wf2, bf2, out);

    // ---------- layer 2 (heads fused into aggregation epilogue) ----------
    gemm_mfma<8, HID><<<gemmBlocks, 256, 0, stream>>>(hbuf, Wp2, al2, ar2,
                                                      feat, el, er);
    gat_aggregate<true><<<nodeWaveBlocks, 256, 0, stream>>>(
        rowptr, csr_src, el, er, feat, nullptr,
        Wc1, bc1, Wc2, bc2, Wf1, bf1, Wf2, bf2, out);
}